// Round 13
// baseline (5870.038 us; speedup 1.0000x reference)
//
#include <hip/hip_runtime.h>

typedef _Float16 half2_t __attribute__((ext_vector_type(2)));
typedef int i32x4 __attribute__((ext_vector_type(4)));

#define NB 64
#define NT 2048
#define ND 256
#define NH 256
#define NTHR 512
#define NCONS 4
#define NPROD 96
#define GRID (NCONS + NPROD)
#define CHUNK 32
#define NCHUNK (NT / CHUNK)   // 64

// ---- consumer LDS byte map ----
#define WHT_OFF 0         // 64 KB  int8 WhT[256 c][256 k], k XOR-swizzled by col
#define HA_OFF  65536     // 4 KB   int8 hA[16 b][256 k], k XOR-swizzled by row
#define VA_OFF  69632     // 4 KB   int8 vA[16 b][256 k], swz
#define HP_OFF  73728     // fp32 hprev[16][265] (odd stride -> conflict-free)
#define HP_STR  265
#define LDS_BYTES (HP_OFF + 16 * HP_STR * 4)   // 90688
// producer reuses first 32 KB as half2 xl[2][32][128]

#define AT_LD(p)    __hip_atomic_load((p), __ATOMIC_RELAXED, __HIP_MEMORY_SCOPE_AGENT)
#define AT_ST(p, v) __hip_atomic_store((p), (v), __ATOMIC_RELAXED, __HIP_MEMORY_SCOPE_AGENT)

__device__ __forceinline__ float sigmoid_f(float x) { return 1.f / (1.f + __expf(-x)); }
__device__ __forceinline__ float tanh_f(float x)    { return 1.f - 2.f / (1.f + __expf(2.f * x)); }
__device__ __forceinline__ half2_t mkh2(float a, float b) {
    half2_t r; r.x = (_Float16)a; r.y = (_Float16)b; return r;
}
__device__ __forceinline__ half2_t u2h2(unsigned u) { return __builtin_bit_cast(half2_t, u); }
__device__ __forceinline__ float h16f(unsigned short u) {
    return (float)__builtin_bit_cast(_Float16, u);
}
__device__ __forceinline__ i32x4 mfma_i8(i32x4 a, i32x4 b, i32x4 c) {
    return __builtin_amdgcn_mfma_i32_16x16x64_i8(a, b, c, 0, 0, 0);
}
// barrier draining only LDS (lgkm); global loads/stores stay in flight.
#define BAR_LDS() asm volatile("s_waitcnt lgkmcnt(0)\n\ts_barrier" ::: "memory")

// Grid 100 x 512, all co-resident (1 WG/CU via 90KB LDS).
//  bid < 4  : consumer — 16 batches (M dim of MFMA). 8 waves x 32 cols.
//             z,r int8 B-frags in VGPRs; Wh int8 in LDS (XOR-swz, b128 frags);
//             h/v as int8 MFMA A-operands in LDS; h_prev exact fp32 in LDS.
//  bid >= 4 : producer (gate g, batches b0..b0+1) — x-projections to ring
//             in [slot][g][bgrp16][c][16b] fp16 layout (4B agent atomics).
extern "C" __global__ void __launch_bounds__(NTHR)
gru_fused(const float* __restrict__ x,
          const float* __restrict__ Wz, const float* __restrict__ bz,
          const float* __restrict__ Wr, const float* __restrict__ br,
          const float* __restrict__ Wh, const float* __restrict__ bh,
          float* __restrict__ out,
          unsigned* prodflag, unsigned* consflag,
          unsigned short* pre, int ring)
{
    __shared__ __align__(16) unsigned smem_u[LDS_BYTES / 4];
    char* smem = (char*)smem_u;
    const int tid = threadIdx.x;
    const int bid = blockIdx.x;
    const int rmask = ring - 1;

    if (bid >= NCONS) {
        // ---------------- producer ----------------
        const int pg   = bid - NCONS;   // 0..95
        const int g    = pg >> 5;       // 0=z 1=r 2=h
        const int s    = pg & 31;       // 2-batch group
        const int b0   = s * 2;
        const int bgrp = s >> 3;        // consumer group 0..3
        const float* W    = (g == 0) ? Wz : (g == 1) ? Wr : Wh;
        const float* bias = (g == 0) ? bz : (g == 1) ? br : bh;
        const int c  = tid >> 1;        // col 0..255
        const int kh = tid & 1;         // k-half of x part

        half2_t w2[64];                 // x-part rows kh*128..+127, col c
        #pragma unroll
        for (int j = 0; j < 64; ++j)
            w2[j] = mkh2(W[(kh * 128 + 2 * j) * NH + c],
                         W[(kh * 128 + 2 * j + 1) * NH + c]);
        const float bv = bias[c];
        half2_t* xl = (half2_t*)smem;   // [2][32][128]

        for (int ch = 0; ch < NCHUNK; ++ch) {
            const int lead = ch * CHUNK + CHUNK - ring;
            if (lead > 0) {
                if (tid == 0) {
                    unsigned it = 0;
                    while ((int)AT_LD(&consflag[bgrp]) < lead) {
                        __builtin_amdgcn_s_sleep(8);
                        if (++it > (1u << 20)) break;
                    }
                }
                __syncthreads();
            }
            const int t0 = ch * CHUNK;
            // stage x[b0..b0+1][t0..t0+31][:] -> fp16 LDS
            #pragma unroll
            for (int rep = 0; rep < 8; ++rep) {
                const int f  = rep * NTHR + tid;   // 0..4095 float4s
                const int bi = f >> 11;
                const int tt = (f >> 6) & 31;
                const int u  = f & 63;
                const float4 v = *reinterpret_cast<const float4*>(
                    x + (((size_t)(b0 + bi) * NT + t0 + tt) * ND + u * 4));
                xl[(bi * 32 + tt) * 128 + u * 2]     = mkh2(v.x, v.y);
                xl[(bi * 32 + tt) * 128 + u * 2 + 1] = mkh2(v.z, v.w);
            }
            __syncthreads();
            #pragma unroll 1
            for (int t = 0; t < CHUNK; ++t) {
                float ab[2];
                #pragma unroll
                for (int bi = 0; bi < 2; ++bi) {
                    const uint4* xr = reinterpret_cast<const uint4*>(
                        xl + (bi * 32 + t) * 128 + kh * 64);
                    float a0 = 0.f, a1 = 0.f, a2 = 0.f, a3 = 0.f;
                    #pragma unroll
                    for (int i = 0; i < 16; ++i) {
                        const uint4 xv = xr[i];
                        a0 = __builtin_amdgcn_fdot2(u2h2(xv.x), w2[i*4+0], a0, false);
                        a1 = __builtin_amdgcn_fdot2(u2h2(xv.y), w2[i*4+1], a1, false);
                        a2 = __builtin_amdgcn_fdot2(u2h2(xv.z), w2[i*4+2], a2, false);
                        a3 = __builtin_amdgcn_fdot2(u2h2(xv.w), w2[i*4+3], a3, false);
                    }
                    float a = (a0 + a1) + (a2 + a3);
                    a += __shfl_xor(a, 1, 64);     // combine k-halves
                    ab[bi] = a + bv;
                }
                if (!(tid & 1)) {
                    const unsigned pk = __builtin_bit_cast(unsigned, mkh2(ab[0], ab[1]));
                    const int slot = (t0 + t) & rmask;
                    const size_t idx = ((((size_t)slot * 3 + g) * 4 + bgrp) * 256 + c) * 16
                                       + (b0 & 15);
                    AT_ST((unsigned*)(pre + idx), pk);
                }
            }
            asm volatile("s_waitcnt vmcnt(0)" ::: "memory");
            __syncthreads();
            if (tid == 0) AT_ST(&prodflag[pg], (unsigned)(ch + 1));
            __syncthreads();
        }
        return;
    }

    // ---------------- consumer: 16 batches via MFMA ----------------
    const int bg   = bid;            // group 0..3, batches bg*16..+15
    const int B0   = bg * 16;
    const int w    = tid >> 6;       // wave 0..7 -> cols w*32..+31
    const int l    = tid & 63;
    const int lr   = l & 15;         // A row / B,C col within tile
    const int lg   = l >> 4;         // k-group / C row-group
    const int r0   = lg * 4;         // C rows r0..r0+3
    const int colN[2] = { w * 32 + lr, w * 32 + 16 + lr };

    // per-lane column scales (own 2 cols x 3 gates)
    float mx[2][3] = {{1e-8f,1e-8f,1e-8f},{1e-8f,1e-8f,1e-8f}};
    for (int k = 0; k < 256; ++k) {
        #pragma unroll
        for (int nt = 0; nt < 2; ++nt) {
            mx[nt][0] = fmaxf(mx[nt][0], fabsf(Wz[(ND + k) * NH + colN[nt]]));
            mx[nt][1] = fmaxf(mx[nt][1], fabsf(Wr[(ND + k) * NH + colN[nt]]));
            mx[nt][2] = fmaxf(mx[nt][2], fabsf(Wh[(ND + k) * NH + colN[nt]]));
        }
    }
    float dqz[2], dqr[2], dqh[2];
    #pragma unroll
    for (int nt = 0; nt < 2; ++nt) {
        dqz[nt] = mx[nt][0] / 16129.f;
        dqr[nt] = mx[nt][1] / 16129.f;
        dqh[nt] = mx[nt][2] / 16129.f;
    }
    // z,r B-fragments in registers: B[k][col], lane: col=lr, k=lg*16+j
    i32x4 bzf[2][4], brf[2][4];
    #pragma unroll
    for (int nt = 0; nt < 2; ++nt) {
        const int col = colN[nt];
        const float qz = 127.f / mx[nt][0], qr = 127.f / mx[nt][1];
        #pragma unroll
        for (int kt = 0; kt < 4; ++kt) {
            int dz[4], dr[4];
            #pragma unroll
            for (int d = 0; d < 4; ++d) {
                unsigned az = 0, ar = 0;
                #pragma unroll
                for (int b = 0; b < 4; ++b) {
                    const int k = kt * 64 + lg * 16 + d * 4 + b;
                    int q1 = __float2int_rn(Wz[(ND + k) * NH + col] * qz);
                    int q2 = __float2int_rn(Wr[(ND + k) * NH + col] * qr);
                    q1 = q1 > 127 ? 127 : (q1 < -127 ? -127 : q1);
                    q2 = q2 > 127 ? 127 : (q2 < -127 ? -127 : q2);
                    az |= ((unsigned)(q1 & 255)) << (8 * b);
                    ar |= ((unsigned)(q2 & 255)) << (8 * b);
                }
                dz[d] = (int)az; dr[d] = (int)ar;
            }
            bzf[nt][kt] = (i32x4){dz[0], dz[1], dz[2], dz[3]};
            brf[nt][kt] = (i32x4){dr[0], dr[1], dr[2], dr[3]};
        }
    }
    // build WhT int8 in LDS (thread: col c=tid>>1, k-half kh)
    {
        const int c  = tid >> 1;
        const int kh = tid & 1;
        float mh = 1e-8f;
        for (int k = 0; k < 256; ++k) mh = fmaxf(mh, fabsf(Wh[(ND + k) * NH + c]));
        const float qs = 127.f / mh;
        for (int d = 0; d < 32; ++d) {
            const int k0 = kh * 128 + d * 4;
            unsigned dw = 0;
            #pragma unroll
            for (int b = 0; b < 4; ++b) {
                int q = __float2int_rn(Wh[(ND + k0 + b) * NH + c] * qs);
                q = q > 127 ? 127 : (q < -127 ? -127 : q);
                dw |= ((unsigned)(q & 255)) << (8 * b);
            }
            smem_u[(WHT_OFF + c * 256 + (k0 ^ ((c & 7) << 4))) >> 2] = dw;
        }
    }
    // zero hA, vA, hprev
    for (int i = tid; i < (LDS_BYTES - HA_OFF) / 4; i += NTHR)
        smem_u[HA_OFF / 4 + i] = 0u;

    // wait for chunk 0 of all 24 feeding producers
    if (tid < 24) {
        const int pg = (tid / 8) * 32 + bg * 8 + (tid % 8);
        unsigned it = 0;
        while (AT_LD(&prodflag[pg]) < 1u) {
            __builtin_amdgcn_s_sleep(8);
            if (++it > (1u << 20)) break;
        }
    }
    __syncthreads();

    const char* hA = smem + HA_OFF;
    char* vAw = smem + VA_OFF;
    char* hAw = smem + HA_OFF;
    float* hpf = (float*)(smem + HP_OFF);
    const int ksw = lg * 16;               // lane's k sub-offset within a k-tile

    #pragma unroll 1
    for (int t = 0; t < NT; ++t) {
        if (t && !(t & (CHUNK - 1))) {     // chunk boundary
            if (tid == 0) AT_ST(&consflag[bg], (unsigned)t);
            const unsigned need = (unsigned)((t >> 5) + 1);
            if (tid < 24) {
                const int pg = (tid / 8) * 32 + bg * 8 + (tid % 8);
                unsigned it = 0;
                while (AT_LD(&prodflag[pg]) < need) {
                    __builtin_amdgcn_s_sleep(8);
                    if (++it > (1u << 20)) break;
                }
            }
            __syncthreads();
        }
        const int slot = t & rmask;
        // this step's pre-activations: 8B per (gate, ntile) -> 4 fp16 rows
        unsigned long long pz[2], pr[2], ph[2];
        #pragma unroll
        for (int nt = 0; nt < 2; ++nt) {
            const size_t cb = (size_t)slot * 3 * 4 + bg;   // base helper
            pz[nt] = AT_LD((const unsigned long long*)(pre +
                     ((((size_t)slot * 3 + 0) * 4 + bg) * 256 + colN[nt]) * 16 + r0));
            pr[nt] = AT_LD((const unsigned long long*)(pre +
                     ((((size_t)slot * 3 + 1) * 4 + bg) * 256 + colN[nt]) * 16 + r0));
            ph[nt] = AT_LD((const unsigned long long*)(pre +
                     ((((size_t)slot * 3 + 2) * 4 + bg) * 256 + colN[nt]) * 16 + r0));
            (void)cb;
        }

        // ---- stage A: z,r GEMMs over hA ----
        i32x4 zc[2] = {(i32x4){0,0,0,0}, (i32x4){0,0,0,0}};
        i32x4 rc[2] = {(i32x4){0,0,0,0}, (i32x4){0,0,0,0}};
        #pragma unroll
        for (int kt = 0; kt < 4; ++kt) {
            const i32x4 ha = *(const i32x4*)(hA + lr * 256 +
                               ((kt * 64 + ksw) ^ ((lr & 7) << 4)));
            zc[0] = mfma_i8(ha, bzf[0][kt], zc[0]);
            zc[1] = mfma_i8(ha, bzf[1][kt], zc[1]);
            rc[0] = mfma_i8(ha, brf[0][kt], rc[0]);
            rc[1] = mfma_i8(ha, brf[1][kt], rc[1]);
        }
        // epilogue A: sigmoid gates, v = r*h_prev -> int8 vA
        float zz[2][4];
        #pragma unroll
        for (int nt = 0; nt < 2; ++nt) {
            const int col = colN[nt];
            #pragma unroll
            for (int i = 0; i < 4; ++i) {
                const int row = r0 + i;
                const float zf = (float)zc[nt][i] * dqz[nt]
                               + h16f((unsigned short)(pz[nt] >> (16 * i)));
                const float rf = (float)rc[nt][i] * dqr[nt]
                               + h16f((unsigned short)(pr[nt] >> (16 * i)));
                const float z = sigmoid_f(zf);
                const float r = sigmoid_f(rf);
                const float hp = hpf[row * HP_STR + col];
                const float v = r * hp;
                vAw[row * 256 + (col ^ ((row & 7) << 4))] =
                    (char)__float2int_rn(v * 127.f);
                zz[nt][i] = z;
            }
        }
        BAR_LDS();   // vA complete

        // ---- stage B: h_hat GEMM over vA (Wh frags from LDS) ----
        i32x4 hc[2] = {(i32x4){0,0,0,0}, (i32x4){0,0,0,0}};
        #pragma unroll
        for (int kt = 0; kt < 4; ++kt) {
            const i32x4 va = *(const i32x4*)(smem + VA_OFF + lr * 256 +
                               ((kt * 64 + ksw) ^ ((lr & 7) << 4)));
            const i32x4 wh0 = *(const i32x4*)(smem + WHT_OFF + colN[0] * 256 +
                               ((kt * 64 + ksw) ^ ((colN[0] & 7) << 4)));
            const i32x4 wh1 = *(const i32x4*)(smem + WHT_OFF + colN[1] * 256 +
                               ((kt * 64 + ksw) ^ ((colN[1] & 7) << 4)));
            hc[0] = mfma_i8(va, wh0, hc[0]);
            hc[1] = mfma_i8(va, wh1, hc[1]);
        }
        // epilogue B: tanh, blend, store out, update h state
        #pragma unroll
        for (int nt = 0; nt < 2; ++nt) {
            const int col = colN[nt];
            #pragma unroll
            for (int i = 0; i < 4; ++i) {
                const int row = r0 + i;
                const float hf = (float)hc[nt][i] * dqh[nt]
                               + h16f((unsigned short)(ph[nt] >> (16 * i)));
                const float hhat = tanh_f(hf);
                const float hp = hpf[row * HP_STR + col];
                const float hn = hp + zz[nt][i] * (hhat - hp);
                out[((size_t)(B0 + row) * NT + t) * NH + col] = hn;
                hpf[row * HP_STR + col] = hn;
                hAw[row * 256 + (col ^ ((row & 7) << 4))] =
                    (char)__float2int_rn(hn * 127.f);
            }
        }
        BAR_LDS();   // hA/hprev = h_t everywhere
    }
}

extern "C" void kernel_launch(void* const* d_in, const int* in_sizes, int n_in,
                              void* d_out, int out_size, void* d_ws, size_t ws_size,
                              hipStream_t stream) {
    const float* x  = (const float*)d_in[0];
    const float* Wz = (const float*)d_in[1];
    const float* bz = (const float*)d_in[2];
    const float* Wr = (const float*)d_in[3];
    const float* br = (const float*)d_in[4];
    const float* Wh = (const float*)d_in[5];
    const float* bh = (const float*)d_in[6];
    float* outp = (float*)d_out;

    // ring sizing: per-slot bytes = 3*4*256*16*2 = 98304
    const size_t base = 4096;
    int ring = 32;
    for (int r = 2048; r >= 32; r >>= 1) {
        const size_t need = base + (size_t)r * 98304;
        if (need <= ws_size) { ring = r; break; }
    }
    char* w = (char*)d_ws;
    unsigned* prodflag = (unsigned*)w;              // [96]
    unsigned* consflag = (unsigned*)(w + 1024);     // [4]
    unsigned short* pre = (unsigned short*)(w + base);  // [ring][3][4][256][16]

    hipMemsetAsync(w, 0, 4096, stream);  // flags must start at 0 each launch
    gru_fused<<<GRID, NTHR, 0, stream>>>(x, Wz, bz, Wr, br, Wh, bh, outp,
                                         prodflag, consflag, pre, ring);
}